// Round 1
// baseline (1404.212 us; speedup 1.0000x reference)
//
#include <hip/hip_runtime.h>

// ---------------- problem constants ----------------
#define T_STEPS 16
#define BATCH   64
#define M_ROWS  1024          // T*B
#define K_DIM   60000
#define N1      200           // layer-1 width
#define N2      50
#define N3      2

// ---------------- GEMM-1 tiling ----------------
#define TM 128
#define TN 40
#define KC 32
#define KSPLIT 16
#define KSEG  (K_DIM / KSPLIT)   // 3750

// part layout: [KSPLIT][M_ROWS][N1] f32
#define PART_ELEMS ((size_t)KSPLIT * M_ROWS * N1)

// Kernel A: partial GEMM  H1_part[s] = X[:, seg_s] @ W1[:, seg_s].T
// grid (M/TM=8, N1/TN=5, KSPLIT=16), block 256
__global__ __launch_bounds__(256)
void gemm1_kernel(const float* __restrict__ x, const float* __restrict__ w1,
                  float* __restrict__ part) {
    __shared__ float xs[KC][TM + 4];   // transposed: xs[k][m]
    __shared__ float ws[KC][TN + 4];   // transposed: ws[k][n]

    const int mt = blockIdx.x, nt = blockIdx.y, s = blockIdx.z;
    const int tid = threadIdx.x;
    const int k0 = s * KSEG, kend = k0 + KSEG;

    const int tcol = tid & 7;    // 8 n-groups of 5
    const int trow = tid >> 3;   // 32 m-groups of 4

    float acc[4][5];
    #pragma unroll
    for (int i = 0; i < 4; ++i)
        #pragma unroll
        for (int j = 0; j < 5; ++j) acc[i][j] = 0.f;

    for (int kb = k0; kb < kend; kb += KC) {
        // stage x tile [TM][KC] -> xs[k][m]
        for (int o = tid; o < TM * KC; o += 256) {
            int r = o >> 5, kk = o & 31;
            int k = kb + kk;
            xs[kk][r] = (k < kend) ? x[(size_t)(mt * TM + r) * K_DIM + k] : 0.f;
        }
        // stage w1 tile [TN][KC] -> ws[k][n]
        for (int o = tid; o < TN * KC; o += 256) {
            int r = o >> 5, kk = o & 31;
            int k = kb + kk;
            ws[kk][r] = (k < kend) ? w1[(size_t)(nt * TN + r) * K_DIM + k] : 0.f;
        }
        __syncthreads();

        #pragma unroll
        for (int kk = 0; kk < KC; ++kk) {
            float xv[4], wv[5];
            #pragma unroll
            for (int i = 0; i < 4; ++i) xv[i] = xs[kk][trow * 4 + i];
            #pragma unroll
            for (int j = 0; j < 5; ++j) wv[j] = ws[kk][tcol * 5 + j];
            #pragma unroll
            for (int i = 0; i < 4; ++i)
                #pragma unroll
                for (int j = 0; j < 5; ++j) acc[i][j] += xv[i] * wv[j];
        }
        __syncthreads();
    }

    #pragma unroll
    for (int i = 0; i < 4; ++i)
        #pragma unroll
        for (int j = 0; j < 5; ++j) {
            int m = mt * TM + trow * 4 + i;
            int n = nt * TN + tcol * 5 + j;
            part[((size_t)s * M_ROWS + m) * N1 + n] = acc[i][j];
        }
}

// Kernel B: reduce K-split partials (deterministic, s-ascending), run LIF-1
// recurrence privately per (b,i), emit spike bitmasks per (t, b, wave-chunk).
// grid 64 (=b), block 256 (i = tid, active i < 200; i padded to 4 waves)
__global__ __launch_bounds__(256)
void lif1_kernel(const float* __restrict__ part,
                 unsigned long long* __restrict__ masks) {
    const int b = blockIdx.x;
    const int i = threadIdx.x;
    const int w = i >> 6;        // wave index 0..3
    float v = 0.f;

    for (int t = 0; t < T_STEPS; ++t) {
        float h = 0.f;
        if (i < N1) {
            size_t base = (size_t)(t * BATCH + b) * N1 + i;
            #pragma unroll
            for (int s = 0; s < KSPLIT; ++s)
                h += part[(size_t)s * M_ROWS * N1 + base];
        }
        v += (h - v) * 0.5f;                 // v + (inp - v)/tau, tau=2
        bool sp = (v - 1.0f) >= 0.f;         // heaviside(v - v_th)
        unsigned long long m = __ballot(sp);
        if (sp) v = 0.f;                     // hard reset: v*(1-s)
        if ((i & 63) == 0) masks[(size_t)(t * BATCH + b) * 4 + w] = m;
    }
}

// Kernel C: sequential layers 2-3. One wave; thread = batch index.
// v2[50], v3[2] live in registers; spikes processed via ctz over bitmasks.
__global__ __launch_bounds__(64)
void seq23_kernel(const unsigned long long* __restrict__ masks,
                  const float* __restrict__ w2, const float* __restrict__ w3,
                  float* __restrict__ out) {
    const int b = threadIdx.x;   // 0..63

    float v2[N2];
    #pragma unroll
    for (int j = 0; j < N2; ++j) v2[j] = 0.f;
    float v3[N3] = {0.f, 0.f};

    for (int t = 0; t < T_STEPS; ++t) {
        float h2[N2];
        #pragma unroll
        for (int j = 0; j < N2; ++j) h2[j] = 0.f;

        // h2[j] = sum over spiking i of W2[j][i]  (i ascending: deterministic)
        #pragma unroll
        for (int w = 0; w < 4; ++w) {
            unsigned long long m = masks[(size_t)(t * BATCH + b) * 4 + w];
            while (m) {
                int l = __builtin_ctzll(m);
                m &= m - 1;
                int i = w * 64 + l;
                #pragma unroll
                for (int j = 0; j < N2; ++j) h2[j] += w2[j * N1 + i];
            }
        }

        // LIF layer 2
        unsigned long long s2m = 0ull;
        #pragma unroll
        for (int j = 0; j < N2; ++j) {
            v2[j] += (h2[j] - v2[j]) * 0.5f;
            bool sp = (v2[j] - 1.0f) >= 0.f;
            if (sp) { s2m |= (1ull << j); v2[j] = 0.f; }
        }

        // h3[c] = sum over spiking j of W3[c][j]
        float h3[N3] = {0.f, 0.f};
        unsigned long long m = s2m;
        while (m) {
            int j = __builtin_ctzll(m);
            m &= m - 1;
            h3[0] += w3[j];
            h3[1] += w3[N2 + j];
        }

        // LIF layer 3 -> output spikes
        #pragma unroll
        for (int c = 0; c < N3; ++c) {
            v3[c] += (h3[c] - v3[c]) * 0.5f;
            bool sp = (v3[c] - 1.0f) >= 0.f;
            out[(size_t)(t * BATCH + b) * N3 + c] = sp ? 1.f : 0.f;
            if (sp) v3[c] = 0.f;
        }
    }
}

extern "C" void kernel_launch(void* const* d_in, const int* in_sizes, int n_in,
                              void* d_out, int out_size, void* d_ws, size_t ws_size,
                              hipStream_t stream) {
    const float* x  = (const float*)d_in[0];   // [16,64,150,400] -> [1024][60000]
    const float* w1 = (const float*)d_in[1];   // [200][60000]
    const float* w2 = (const float*)d_in[2];   // [50][200]
    const float* w3 = (const float*)d_in[3];   // [2][50]
    float* out = (float*)d_out;                // [16][64][2]

    float* part = (float*)d_ws;                                   // 13.1 MB
    unsigned long long* masks =
        (unsigned long long*)((char*)d_ws + PART_ELEMS * sizeof(float)); // 32 KB

    dim3 grid_a(M_ROWS / TM, N1 / TN, KSPLIT);
    gemm1_kernel<<<grid_a, 256, 0, stream>>>(x, w1, part);
    lif1_kernel<<<BATCH, 256, 0, stream>>>(part, masks);
    seq23_kernel<<<1, 64, 0, stream>>>(masks, w2, w3, out);
}

// Round 2
// 307.142 us; speedup vs baseline: 4.5719x; 4.5719x over previous
//
#include <hip/hip_runtime.h>

// ---------------- problem constants ----------------
#define T_STEPS 16
#define BATCH   64
#define M_ROWS  1024          // T*B
#define K_DIM   60000
#define N1      200
#define N2      50
#define N3      2

// ---------------- MFMA GEMM tiling ----------------
#define BM 128
#define BN 256                // N1 padded to 256 (cols >=200 zero, never stored)
#define BK 32
#define KSPLIT 25
#define KSEG   (K_DIM / KSPLIT)   // 2400
#define KSTEPS (KSEG / BK)        // 75

#define PART_ELEMS ((size_t)KSPLIT * M_ROWS * N1)   // 5.12M f32 = 20.5 MB

typedef __attribute__((ext_vector_type(8))) short    bf16x8;
typedef __attribute__((ext_vector_type(4))) float    f32x4;
typedef __attribute__((ext_vector_type(8))) unsigned short u16x8;

static __device__ __forceinline__ unsigned short f2bf(float f) {
    // round-to-nearest-even f32 -> bf16 (inputs are finite normals)
    unsigned int u = __float_as_uint(f);
    u += 0x7FFFu + ((u >> 16) & 1u);
    return (unsigned short)(u >> 16);
}

// Kernel A: H1_part[s] = X[:, seg_s] @ W1[:, seg_s].T   via bf16 MFMA
// grid (8 m-tiles, 25 k-splits), block 256 (4 waves, 2x2 of 64x128)
__global__ __launch_bounds__(256, 2)
void gemm1_mfma(const float* __restrict__ x, const float* __restrict__ w1,
                float* __restrict__ part) {
    __shared__ unsigned short xs[2][BM * BK];   // [m][k] row-major, 8KB each
    __shared__ unsigned short ws[2][BN * BK];   // [n][k] row-major, 16KB each

    const int mt  = blockIdx.x;
    const int s   = blockIdx.y;
    const int tid = threadIdx.x;
    const int l   = tid & 63;
    const int wv  = tid >> 6;
    const int wm  = (wv & 1) * 64;    // wave m-offset in tile
    const int wn  = (wv >> 1) * 128;  // wave n-offset in tile
    const int m0  = mt * BM;
    const int k0  = s * KSEG;

    const int srow = tid >> 2;        // 0..63 staging row group
    const int sc   = (tid & 3) * 8;   // k-offset (elements) within BK

    f32x4 acc[4][8];
    #pragma unroll
    for (int i = 0; i < 4; ++i)
        #pragma unroll
        for (int j = 0; j < 8; ++j) acc[i][j] = (f32x4){0.f, 0.f, 0.f, 0.f};

    float4 ldx[2][2];   // 2 x-chunks x 8 floats
    float4 ldw[4][2];   // 4 w-chunks x 8 floats

    // ---- prologue: stage step 0 into buffer 0 ----
    {
        const int kb = k0;
        #pragma unroll
        for (int r = 0; r < 2; ++r) {
            const float* g = x + (size_t)(m0 + srow + r * 64) * K_DIM + kb + sc;
            ldx[r][0] = *(const float4*)g;
            ldx[r][1] = *(const float4*)(g + 4);
        }
        #pragma unroll
        for (int r = 0; r < 4; ++r) {
            int row = srow + r * 64;
            if (row < N1) {
                const float* g = w1 + (size_t)row * K_DIM + kb + sc;
                ldw[r][0] = *(const float4*)g;
                ldw[r][1] = *(const float4*)(g + 4);
            }
        }
        #pragma unroll
        for (int r = 0; r < 2; ++r) {
            u16x8 v;
            #pragma unroll
            for (int q = 0; q < 4; ++q) { v[q] = f2bf(ldx[r][0][q]); v[q+4] = f2bf(ldx[r][1][q]); }
            *(u16x8*)&xs[0][(srow + r * 64) * BK + sc] = v;
        }
        #pragma unroll
        for (int r = 0; r < 4; ++r) {
            int row = srow + r * 64;
            u16x8 v = (u16x8){0,0,0,0,0,0,0,0};
            if (row < N1) {
                #pragma unroll
                for (int q = 0; q < 4; ++q) { v[q] = f2bf(ldw[r][0][q]); v[q+4] = f2bf(ldw[r][1][q]); }
            }
            *(u16x8*)&ws[0][row * BK + sc] = v;
        }
    }

    const int arow = l & 15;          // fragment row (m) / row (n)
    const int koff = (l >> 4) * 8;    // fragment k-offset (elements)

    for (int it = 0; it < KSTEPS; ++it) {
        __syncthreads();
        const int cur = it & 1;
        const bool more = (it + 1) < KSTEPS;

        // T14 issue-early: global loads for step it+1 (latency hides under MFMA)
        if (more) {
            const int kb = k0 + (it + 1) * BK;
            #pragma unroll
            for (int r = 0; r < 2; ++r) {
                const float* g = x + (size_t)(m0 + srow + r * 64) * K_DIM + kb + sc;
                ldx[r][0] = *(const float4*)g;
                ldx[r][1] = *(const float4*)(g + 4);
            }
            #pragma unroll
            for (int r = 0; r < 4; ++r) {
                int row = srow + r * 64;
                if (row < N1) {
                    const float* g = w1 + (size_t)row * K_DIM + kb + sc;
                    ldw[r][0] = *(const float4*)g;
                    ldw[r][1] = *(const float4*)(g + 4);
                }
            }
        }

        // compute on LDS[cur]
        bf16x8 af[4];
        #pragma unroll
        for (int fm = 0; fm < 4; ++fm)
            af[fm] = *(const bf16x8*)&xs[cur][(wm + fm * 16 + arow) * BK + koff];
        #pragma unroll
        for (int fn = 0; fn < 8; ++fn) {
            bf16x8 bf = *(const bf16x8*)&ws[cur][(wn + fn * 16 + arow) * BK + koff];
            #pragma unroll
            for (int fm = 0; fm < 4; ++fm)
                acc[fm][fn] = __builtin_amdgcn_mfma_f32_16x16x32_bf16(af[fm], bf, acc[fm][fn], 0, 0, 0);
        }

        // write-late: cvt + ds_write into LDS[cur^1]
        if (more) {
            const int nb = cur ^ 1;
            #pragma unroll
            for (int r = 0; r < 2; ++r) {
                u16x8 v;
                #pragma unroll
                for (int q = 0; q < 4; ++q) { v[q] = f2bf(ldx[r][0][q]); v[q+4] = f2bf(ldx[r][1][q]); }
                *(u16x8*)&xs[nb][(srow + r * 64) * BK + sc] = v;
            }
            #pragma unroll
            for (int r = 0; r < 4; ++r) {
                int row = srow + r * 64;
                u16x8 v = (u16x8){0,0,0,0,0,0,0,0};
                if (row < N1) {
                    #pragma unroll
                    for (int q = 0; q < 4; ++q) { v[q] = f2bf(ldw[r][0][q]); v[q+4] = f2bf(ldw[r][1][q]); }
                }
                *(u16x8*)&ws[nb][row * BK + sc] = v;
            }
        }
    }

    // ---- epilogue: store cols < 200 packed [s][m][n], ld = 200 ----
    const int crow = (l >> 4) * 4;
    const int ccol = l & 15;
    #pragma unroll
    for (int fm = 0; fm < 4; ++fm) {
        #pragma unroll
        for (int fn = 0; fn < 8; ++fn) {
            const int gn = wn + fn * 16 + ccol;
            if (gn < N1) {
                const int gm = m0 + wm + fm * 16 + crow;
                float* p = part + ((size_t)s * M_ROWS + gm) * N1 + gn;
                #pragma unroll
                for (int r = 0; r < 4; ++r) p[(size_t)r * N1] = acc[fm][fn][r];
            }
        }
    }
}

// Kernel B: deterministic s-ascending reduction of partials + private LIF-1
// recurrence per (b,i); emits spike bitmasks. grid 64, block 256.
__global__ __launch_bounds__(256)
void lif1_kernel(const float* __restrict__ part,
                 unsigned long long* __restrict__ masks) {
    const int b = blockIdx.x;
    const int i = threadIdx.x;
    const int w = i >> 6;
    float v = 0.f;

    for (int t = 0; t < T_STEPS; ++t) {
        float h = 0.f;
        if (i < N1) {
            size_t base = (size_t)(t * BATCH + b) * N1 + i;
            #pragma unroll
            for (int s = 0; s < KSPLIT; ++s)
                h += part[(size_t)s * M_ROWS * N1 + base];
        }
        v += (h - v) * 0.5f;                 // v + (inp - v)/tau, tau=2
        bool sp = (v - 1.0f) >= 0.f;
        unsigned long long m = __ballot(sp);
        if (sp) v = 0.f;
        if ((i & 63) == 0) masks[(size_t)(t * BATCH + b) * 4 + w] = m;
    }
}

// Kernel C: sequential tiny layers 2-3, one wave, thread = batch index.
__global__ __launch_bounds__(64)
void seq23_kernel(const unsigned long long* __restrict__ masks,
                  const float* __restrict__ w2, const float* __restrict__ w3,
                  float* __restrict__ out) {
    const int b = threadIdx.x;

    float v2[N2];
    #pragma unroll
    for (int j = 0; j < N2; ++j) v2[j] = 0.f;
    float v3[N3] = {0.f, 0.f};

    for (int t = 0; t < T_STEPS; ++t) {
        float h2[N2];
        #pragma unroll
        for (int j = 0; j < N2; ++j) h2[j] = 0.f;

        #pragma unroll
        for (int w = 0; w < 4; ++w) {
            unsigned long long m = masks[(size_t)(t * BATCH + b) * 4 + w];
            while (m) {
                int lz = __builtin_ctzll(m);
                m &= m - 1;
                int i = w * 64 + lz;
                #pragma unroll
                for (int j = 0; j < N2; ++j) h2[j] += w2[j * N1 + i];
            }
        }

        unsigned long long s2m = 0ull;
        #pragma unroll
        for (int j = 0; j < N2; ++j) {
            v2[j] += (h2[j] - v2[j]) * 0.5f;
            bool sp = (v2[j] - 1.0f) >= 0.f;
            if (sp) { s2m |= (1ull << j); v2[j] = 0.f; }
        }

        float h3[N3] = {0.f, 0.f};
        unsigned long long m = s2m;
        while (m) {
            int j = __builtin_ctzll(m);
            m &= m - 1;
            h3[0] += w3[j];
            h3[1] += w3[N2 + j];
        }

        #pragma unroll
        for (int c = 0; c < N3; ++c) {
            v3[c] += (h3[c] - v3[c]) * 0.5f;
            bool sp = (v3[c] - 1.0f) >= 0.f;
            out[(size_t)(t * BATCH + b) * N3 + c] = sp ? 1.f : 0.f;
            if (sp) v3[c] = 0.f;
        }
    }
}

extern "C" void kernel_launch(void* const* d_in, const int* in_sizes, int n_in,
                              void* d_out, int out_size, void* d_ws, size_t ws_size,
                              hipStream_t stream) {
    const float* x  = (const float*)d_in[0];   // [16,64,150,400] -> [1024][60000]
    const float* w1 = (const float*)d_in[1];   // [200][60000]
    const float* w2 = (const float*)d_in[2];   // [50][200]
    const float* w3 = (const float*)d_in[3];   // [2][50]
    float* out = (float*)d_out;                // [16][64][2]

    float* part = (float*)d_ws;                                         // 20.5 MB
    unsigned long long* masks =
        (unsigned long long*)((char*)d_ws + PART_ELEMS * sizeof(float)); // 32 KB

    dim3 grid_a(M_ROWS / BM, KSPLIT);
    gemm1_mfma<<<grid_a, 256, 0, stream>>>(x, w1, part);
    lif1_kernel<<<BATCH, 256, 0, stream>>>(part, masks);
    seq23_kernel<<<1, 64, 0, stream>>>(masks, w2, w3, out);
}

// Round 3
// 290.783 us; speedup vs baseline: 4.8291x; 1.0563x over previous
//
#include <hip/hip_runtime.h>

// ---------------- problem constants ----------------
#define T_STEPS 16
#define BATCH   64
#define M_ROWS  1024          // T*B
#define K_DIM   60000
#define N1      200
#define N2      50
#define N3      2

// ---------------- MFMA GEMM tiling ----------------
#define BM 64                 // m-rows per block (16 m-tiles)
#define BN 256                // N1 padded to 256 (cols >=200 zero, never stored)
#define BK 32
#define LDK 40                // padded LDS row stride (shorts): 80B = 5x16B -> conflict-free
#define HN  (M_ROWS * N1)     // 204800 elems per [m][n] slab

typedef __attribute__((ext_vector_type(8))) short    bf16x8;
typedef __attribute__((ext_vector_type(4))) float    f32x4;
typedef __attribute__((ext_vector_type(8))) unsigned short u16x8;

static __device__ __forceinline__ unsigned short f2bf(float f) {
    unsigned int u = __float_as_uint(f);
    u += 0x7FFFu + ((u >> 16) & 1u);      // RNE f32 -> bf16
    return (unsigned short)(u >> 16);
}

// Kernel A: part[s] = X[:, seg_s] @ W1[:, seg_s].T  via bf16 MFMA
// grid (16 m-tiles, KSPLIT), block 256 = 4 waves, each wave 64x64 (BM x BN/4)
template <int KSEG, int KSTEPS>
__global__ __launch_bounds__(256, 3)
void gemm1_mfma(const float* __restrict__ x, const float* __restrict__ w1,
                float* __restrict__ part) {
    __shared__ unsigned short xs[2][BM * LDK];   // 5KB each
    __shared__ unsigned short ws[2][BN * LDK];   // 20KB each

    const int mt  = blockIdx.x;
    const int s   = blockIdx.y;
    const int tid = threadIdx.x;
    const int l   = tid & 63;
    const int wv  = tid >> 6;
    const int wn  = wv * 64;          // wave n-offset in tile
    const int m0  = mt * BM;
    const int k0  = s * KSEG;

    const int srow = tid >> 2;        // 0..63 staging row
    const int sc   = (tid & 3) * 8;   // k-offset (elements) within BK

    f32x4 acc[4][4];
    #pragma unroll
    for (int i = 0; i < 4; ++i)
        #pragma unroll
        for (int j = 0; j < 4; ++j) acc[i][j] = (f32x4){0.f, 0.f, 0.f, 0.f};

    float4 ldx[2];      // 8 floats (one x row-chunk)
    float4 ldw[4][2];   // 4 w row-chunks x 8 floats

    // ---- prologue: load + stage step 0 into buffer 0 ----
    {
        const float* g = x + (size_t)(m0 + srow) * K_DIM + k0 + sc;
        ldx[0] = *(const float4*)g;
        ldx[1] = *(const float4*)(g + 4);
        #pragma unroll
        for (int r = 0; r < 4; ++r) {
            int row = srow + r * 64;
            if (row < N1) {
                const float* gw = w1 + (size_t)row * K_DIM + k0 + sc;
                ldw[r][0] = *(const float4*)gw;
                ldw[r][1] = *(const float4*)(gw + 4);
            }
        }
        u16x8 v;
        #pragma unroll
        for (int q = 0; q < 4; ++q) { v[q] = f2bf(ldx[0][q]); v[q+4] = f2bf(ldx[1][q]); }
        *(u16x8*)&xs[0][srow * LDK + sc] = v;
        #pragma unroll
        for (int r = 0; r < 4; ++r) {
            int row = srow + r * 64;
            u16x8 w = (u16x8){0,0,0,0,0,0,0,0};
            if (row < N1) {
                #pragma unroll
                for (int q = 0; q < 4; ++q) { w[q] = f2bf(ldw[r][0][q]); w[q+4] = f2bf(ldw[r][1][q]); }
            }
            *(u16x8*)&ws[0][row * LDK + sc] = w;
        }
    }

    const int arow = l & 15;          // fragment row within 16
    const int koff = (l >> 4) * 8;    // fragment k-offset (elements)

    for (int it = 0; it < KSTEPS; ++it) {
        __syncthreads();
        const int cur = it & 1;
        const bool more = (it + 1) < KSTEPS;

        // issue-early: global loads for step it+1 hide under MFMA
        if (more) {
            const int kb = k0 + (it + 1) * BK;
            const float* g = x + (size_t)(m0 + srow) * K_DIM + kb + sc;
            ldx[0] = *(const float4*)g;
            ldx[1] = *(const float4*)(g + 4);
            #pragma unroll
            for (int r = 0; r < 4; ++r) {
                int row = srow + r * 64;
                if (row < N1) {
                    const float* gw = w1 + (size_t)row * K_DIM + kb + sc;
                    ldw[r][0] = *(const float4*)gw;
                    ldw[r][1] = *(const float4*)(gw + 4);
                }
            }
        }

        // compute on LDS[cur]
        bf16x8 af[4];
        #pragma unroll
        for (int fm = 0; fm < 4; ++fm)
            af[fm] = *(const bf16x8*)&xs[cur][(fm * 16 + arow) * LDK + koff];
        #pragma unroll
        for (int fn = 0; fn < 4; ++fn) {
            bf16x8 bf = *(const bf16x8*)&ws[cur][(wn + fn * 16 + arow) * LDK + koff];
            #pragma unroll
            for (int fm = 0; fm < 4; ++fm)
                acc[fm][fn] = __builtin_amdgcn_mfma_f32_16x16x32_bf16(af[fm], bf, acc[fm][fn], 0, 0, 0);
        }

        // write-late: cvt + ds_write into LDS[cur^1]
        if (more) {
            const int nb = cur ^ 1;
            u16x8 v;
            #pragma unroll
            for (int q = 0; q < 4; ++q) { v[q] = f2bf(ldx[0][q]); v[q+4] = f2bf(ldx[1][q]); }
            *(u16x8*)&xs[nb][srow * LDK + sc] = v;
            #pragma unroll
            for (int r = 0; r < 4; ++r) {
                int row = srow + r * 64;
                u16x8 w = (u16x8){0,0,0,0,0,0,0,0};
                if (row < N1) {
                    #pragma unroll
                    for (int q = 0; q < 4; ++q) { w[q] = f2bf(ldw[r][0][q]); w[q+4] = f2bf(ldw[r][1][q]); }
                }
                *(u16x8*)&ws[nb][row * LDK + sc] = w;
            }
        }
    }

    // ---- epilogue: store cols < 200, part layout [s][m][n], ld = 200 ----
    const int crow = (l >> 4) * 4;
    const int ccol = l & 15;
    #pragma unroll
    for (int fm = 0; fm < 4; ++fm)
        #pragma unroll
        for (int fn = 0; fn < 4; ++fn) {
            const int gn = wn + fn * 16 + ccol;
            if (gn < N1) {
                const int gm = m0 + fm * 16 + crow;
                float* p = part + (size_t)s * HN + (size_t)gm * N1 + gn;
                #pragma unroll
                for (int r = 0; r < 4; ++r) p[(size_t)r * N1] = acc[fm][fn][r];
            }
        }
}

// Kernel B: dense deterministic s-reduction: h1[f] = sum_s part[s][f]
// grid 800 x 256 (one thread per (t,b,i) element), coalesced
template <int KSPLIT>
__global__ __launch_bounds__(256)
void reduce_kernel(const float* __restrict__ part, float* __restrict__ h1) {
    const size_t f = (size_t)blockIdx.x * 256 + threadIdx.x;   // < 204800
    float acc = 0.f;
    #pragma unroll
    for (int s = 0; s < KSPLIT; ++s) acc += part[(size_t)s * HN + f];
    h1[f] = acc;
}

// Kernel C: private LIF-1 recurrence per (b,i); emits spike bitmasks.
__global__ __launch_bounds__(256)
void lif1_kernel(const float* __restrict__ h1,
                 unsigned long long* __restrict__ masks) {
    const int b = blockIdx.x;
    const int i = threadIdx.x;
    const int w = i >> 6;
    float v = 0.f;

    for (int t = 0; t < T_STEPS; ++t) {
        float h = (i < N1) ? h1[(size_t)(t * BATCH + b) * N1 + i] : 0.f;
        v += (h - v) * 0.5f;                 // v + (inp - v)/tau, tau=2
        bool sp = (v - 1.0f) >= 0.f;
        unsigned long long m = __ballot(sp);
        if (sp) v = 0.f;
        if ((i & 63) == 0) masks[(size_t)(t * BATCH + b) * 4 + w] = m;
    }
}

// Kernel D: sequential tiny layers 2-3, one wave, thread = batch index.
__global__ __launch_bounds__(64)
void seq23_kernel(const unsigned long long* __restrict__ masks,
                  const float* __restrict__ w2, const float* __restrict__ w3,
                  float* __restrict__ out) {
    const int b = threadIdx.x;

    float v2[N2];
    #pragma unroll
    for (int j = 0; j < N2; ++j) v2[j] = 0.f;
    float v3[N3] = {0.f, 0.f};

    for (int t = 0; t < T_STEPS; ++t) {
        float h2[N2];
        #pragma unroll
        for (int j = 0; j < N2; ++j) h2[j] = 0.f;

        #pragma unroll
        for (int w = 0; w < 4; ++w) {
            unsigned long long m = masks[(size_t)(t * BATCH + b) * 4 + w];
            while (m) {
                int lz = __builtin_ctzll(m);
                m &= m - 1;
                int i = w * 64 + lz;
                #pragma unroll
                for (int j = 0; j < N2; ++j) h2[j] += w2[j * N1 + i];
            }
        }

        unsigned long long s2m = 0ull;
        #pragma unroll
        for (int j = 0; j < N2; ++j) {
            v2[j] += (h2[j] - v2[j]) * 0.5f;
            bool sp = (v2[j] - 1.0f) >= 0.f;
            if (sp) { s2m |= (1ull << j); v2[j] = 0.f; }
        }

        float h3[N3] = {0.f, 0.f};
        unsigned long long m = s2m;
        while (m) {
            int j = __builtin_ctzll(m);
            m &= m - 1;
            h3[0] += w3[j];
            h3[1] += w3[N2 + j];
        }

        #pragma unroll
        for (int c = 0; c < N3; ++c) {
            v3[c] += (h3[c] - v3[c]) * 0.5f;
            bool sp = (v3[c] - 1.0f) >= 0.f;
            out[(size_t)(t * BATCH + b) * N3 + c] = sp ? 1.f : 0.f;
            if (sp) v3[c] = 0.f;
        }
    }
}

extern "C" void kernel_launch(void* const* d_in, const int* in_sizes, int n_in,
                              void* d_out, int out_size, void* d_ws, size_t ws_size,
                              hipStream_t stream) {
    const float* x  = (const float*)d_in[0];   // [16,64,150,400] -> [1024][60000]
    const float* w1 = (const float*)d_in[1];   // [200][60000]
    const float* w2 = (const float*)d_in[2];   // [50][200]
    const float* w3 = (const float*)d_in[3];   // [2][50]
    float* out = (float*)d_out;                // [16][64][2]

    // pick KSPLIT by available workspace (75 needs ~62.3 MB)
    const size_t need75 = (size_t)75 * HN * 4 + (size_t)HN * 4 + 32768;
    const bool big = ws_size >= need75;
    const int ksplit = big ? 75 : 25;

    float* part = (float*)d_ws;
    float* h1   = (float*)((char*)d_ws + (size_t)ksplit * HN * 4);
    unsigned long long* masks =
        (unsigned long long*)((char*)h1 + (size_t)HN * 4);

    if (big) {
        dim3 g(M_ROWS / BM, 75);
        gemm1_mfma<800, 25><<<g, 256, 0, stream>>>(x, w1, part);
        reduce_kernel<75><<<HN / 256, 256, 0, stream>>>(part, h1);
    } else {
        dim3 g(M_ROWS / BM, 25);
        gemm1_mfma<2400, 75><<<g, 256, 0, stream>>>(x, w1, part);
        reduce_kernel<25><<<HN / 256, 256, 0, stream>>>(part, h1);
    }
    lif1_kernel<<<BATCH, 256, 0, stream>>>(h1, masks);
    seq23_kernel<<<1, 64, 0, stream>>>(masks, w2, w3, out);
}